// Round 5
// baseline (279.099 us; speedup 1.0000x reference)
//
#include <hip/hip_runtime.h>
#include <hip/hip_bf16.h>
#include <stdint.h>

// ---------------------------------------------------------------------------
// Single-head self-attention, B=4, S=2048, D=1024, fp32 in/out.
// Round 5: distinct kernel names (score/pv visibility in rocprof); qkv
// reverted to plain (tn,tm,z) grid mapping (round-3 known-good; round-4 XCD
// swizzle cut FETCH 137->49MB but cost +12% time — latency, not BW, binds).
// Fused vT epilogue kept. score/pv keep round-4 supertile swizzles.
// Pipeline:
//   1. k_prep: xb=bf16(x); wt=bf16(W^T) q,k,v; rowsum=0
//   2. k_qkv:  q,k = x@W+b (bf16); v -> written TRANSPOSED as vT
//   3. k_score: P' = exp2(q@k^T * s*log2e) (bf16) + rowsum atomics
//   4. k_pv:   out = (P' @ vT^T) / rowsum (fp32 -> d_out)
// ---------------------------------------------------------------------------

typedef __attribute__((ext_vector_type(8))) short short8;   // 8 bf16 = 4 VGPR
typedef __attribute__((ext_vector_type(4))) float f32x4;    // MFMA C/D

__device__ __forceinline__ unsigned short f2bf(float f) {
  union { float f; uint32_t u; } c; c.f = f;
  uint32_t u = c.u;
  u += 0x7FFFu + ((u >> 16) & 1u);   // RNE
  return (unsigned short)(u >> 16);
}

// async global->LDS, 16B/lane; LDS dest is wave-uniform base + lane*16.
__device__ __forceinline__ void gl16(const void* g, void* l) {
  __builtin_amdgcn_global_load_lds(
      (const __attribute__((address_space(1))) unsigned int*)g,
      (__attribute__((address_space(3))) unsigned int*)l, 16, 0, 0);
}

// Shared GEMM body. C = A @ B^T, 128x128 tile, BK=32 double-buffered,
// 4 waves (2x2 of 64x64 each, 4x4 frags of 16x16x32 bf16 MFMA).
// MODE 0 (qkv): K=1024; C bf16 += bias[col]; z==2 writes vT transposed.
// MODE 1 (score): K=1024; C bf16 = exp2(acc*scale); rowsum atomics.
// MODE 2 (pv): K=2048; C fp32 = acc / rowsum[row].
template <int MODE>
__device__ __forceinline__ void gemm_body(
    int z, int tm, int tn,
    const short* __restrict__ A, const short* __restrict__ B,
    void* __restrict__ Cv, short* __restrict__ vT, float scale,
    const float* __restrict__ bias0, const float* __restrict__ bias1,
    const float* __restrict__ bias2, float* __restrict__ rowsum)
{
  constexpr int  LDA = (MODE == 2) ? 2048 : 1024;
  constexpr int  LDB = (MODE == 2) ? 2048 : 1024;
  constexpr int  LDC = (MODE == 0) ? 1024 : ((MODE == 1) ? 2048 : 1024);
  constexpr long SAZ = (MODE == 0) ? 0L : ((MODE == 1) ? 2097152L : 4194304L);
  constexpr long SBZ = (MODE == 0) ? 1048576L : 2097152L;
  constexpr long SCZ = (MODE == 0) ? 8388608L : ((MODE == 1) ? 4194304L : 2097152L);
  constexpr int  T   = (MODE == 2) ? 64 : 32;   // k-tiles of 32

  // staging: buf b at lds + b*8192 shorts (sA 4096 | sB 4096).
  // epilogue overlay: per-wave [64][72] shorts at wid*4608 (36864B total).
  __shared__ short lds[18432];

  const int tid  = threadIdx.x;
  const int lane = tid & 63;
  const int wid  = tid >> 6;
  const long tileM = (long)tm * 128;
  const long tileN = (long)tn * 128;
  const short* Az = A + (long)z * SAZ;
  const short* Bz = B + (long)z * SBZ;

  // per 128x32 tile: 512 x 16B chunks per matrix; chunk c: row=c>>2, col8=c&3
  const int c0 = tid, c1 = 256 + tid;
  const short* gA0 = Az + (tileM + (c0 >> 2)) * LDA + (c0 & 3) * 8;
  const short* gA1 = Az + (tileM + (c1 >> 2)) * LDA + (c1 & 3) * 8;
  const short* gB0 = Bz + (tileN + (c0 >> 2)) * LDB + (c0 & 3) * 8;
  const short* gB1 = Bz + (tileN + (c1 >> 2)) * LDB + (c1 & 3) * 8;

  const int fr = lane & 15, quad = lane >> 4;
  const int waveM = (wid >> 1) * 64, waveN = (wid & 1) * 64;

  f32x4 acc[4][4] = {};

  // prologue: tile 0 -> buf 0
  {
    short* base = lds;
    gl16(gA0, base + c0 * 8);
    gl16(gA1, base + c1 * 8);
    gl16(gB0, base + 4096 + c0 * 8);
    gl16(gB1, base + 4096 + c1 * 8);
  }

  for (int t = 0; t < T; ++t) {
    __syncthreads();   // drains tile t's loads; buf (t+1)&1 readers done
    if (t + 1 < T) {
      const int kt = (t + 1) << 5;
      short* base = lds + ((t + 1) & 1) * 8192;
      gl16(gA0 + kt, base + c0 * 8);
      gl16(gA1 + kt, base + c1 * 8);
      gl16(gB0 + kt, base + 4096 + c0 * 8);
      gl16(gB1 + kt, base + 4096 + c1 * 8);
    }
    const short* sA = lds + (t & 1) * 8192;
    const short* sB = sA + 4096;
    short8 af[4], bf[4];
#pragma unroll
    for (int i = 0; i < 4; ++i)
      af[i] = *(const short8*)&sA[(waveM + i * 16 + fr) * 32 + quad * 8];
#pragma unroll
    for (int j = 0; j < 4; ++j)
      bf[j] = *(const short8*)&sB[(waveN + j * 16 + fr) * 32 + quad * 8];
#pragma unroll
    for (int i = 0; i < 4; ++i)
#pragma unroll
      for (int j = 0; j < 4; ++j)
        acc[i][j] = __builtin_amdgcn_mfma_f32_16x16x32_bf16(af[i], bf[j],
                                                            acc[i][j], 0, 0, 0);
  }

  // C/D layout per frag: row=(lane>>4)*4+r, col=lane&15 (m89/m91-verified).
  if (MODE == 1) {
#pragma unroll
    for (int i = 0; i < 4; ++i)
#pragma unroll
      for (int j = 0; j < 4; ++j)
#pragma unroll
        for (int r = 0; r < 4; ++r)
          acc[i][j][r] = exp2f(acc[i][j][r] * scale);
#pragma unroll
    for (int i = 0; i < 4; ++i)
#pragma unroll
      for (int r = 0; r < 4; ++r) {
        float s = acc[i][0][r] + acc[i][1][r] + acc[i][2][r] + acc[i][3][r];
        s += __shfl_xor(s, 1);
        s += __shfl_xor(s, 2);
        s += __shfl_xor(s, 4);
        s += __shfl_xor(s, 8);
        if (fr == 0)
          atomicAdd(&rowsum[(long)z * 2048 + tileM + waveM + i * 16 + quad * 4 + r], s);
      }
  }

  if (MODE == 0 && z == 2) {
    // v-tile: add bias, write TRANSPOSED scratch [d][t], store to vT[b][d][t]
    __syncthreads();                 // other waves' staging reads done
    short* scr = lds + wid * 4608;   // [64][72]
#pragma unroll
    for (int j = 0; j < 4; ++j) {
      const float bv = bias2[tileN + waveN + j * 16 + fr];
#pragma unroll
      for (int i = 0; i < 4; ++i)
#pragma unroll
        for (int r = 0; r < 4; ++r)
          scr[(j * 16 + fr) * 72 + i * 16 + quad * 4 + r] =
              (short)f2bf(acc[i][j][r] + bv);
    }
    const int gb = tm >> 4;                    // batch
    const long t0 = (long)(tm & 15) * 128 + waveM;
#pragma unroll
    for (int c = 0; c < 8; ++c) {
      const int rr = c * 8 + (lane >> 3);      // d within wave tile
      const int cc = (lane & 7) * 8;           // t within wave tile
      short8 v = *(const short8*)&scr[rr * 72 + cc];
      const long gd = tileN + waveN + rr;
      *(short8*)(vT + ((long)gb << 21) + gd * 2048 + t0 + cc) = v;
    }
  } else if (MODE <= 1) {
    // bf16 out via per-wave LDS transpose -> contiguous dwordx4 stores
    __syncthreads();                 // other waves' staging reads done
    short* scr = lds + wid * 4608;   // [64][72]
    short* C = (short*)Cv + (long)z * SCZ;
    const float* bias = (z == 0) ? bias0 : bias1;
#pragma unroll
    for (int j = 0; j < 4; ++j) {
      const float bv = (MODE == 0) ? bias[tileN + waveN + j * 16 + fr] : 0.0f;
#pragma unroll
      for (int i = 0; i < 4; ++i)
#pragma unroll
        for (int r = 0; r < 4; ++r)
          scr[(i * 16 + quad * 4 + r) * 72 + j * 16 + fr] =
              (short)f2bf(acc[i][j][r] + bv);
    }
    // per-wave scratch: ds_write->ds_read ordering via lgkmcnt (no barrier)
#pragma unroll
    for (int c = 0; c < 8; ++c) {
      const int row = c * 8 + (lane >> 3);
      const int col = (lane & 7) * 8;
      short8 v = *(const short8*)&scr[row * 72 + col];
      *(short8*)(C + (tileM + waveM + row) * LDC + tileN + waveN + col) = v;
    }
  } else {
    // MODE 2: fp32 out, normalized by rowsum
    float* C = (float*)Cv + (long)z * SCZ;
#pragma unroll
    for (int i = 0; i < 4; ++i)
#pragma unroll
      for (int r = 0; r < 4; ++r) {
        const long gr = tileM + waveM + i * 16 + quad * 4 + r;
        const float rinv = 1.0f / rowsum[(long)z * 2048 + gr];
#pragma unroll
        for (int j = 0; j < 4; ++j)
          C[gr * LDC + tileN + waveN + j * 16 + fr] = acc[i][j][r] * rinv;
      }
  }
}

// qkv: plain round-3 mapping — grid dim3(8,64,3): x=tn, y=tm, z=z.
__global__ __launch_bounds__(256) void k_qkv(
    const short* __restrict__ A, const short* __restrict__ B,
    void* __restrict__ Cv, short* __restrict__ vT,
    const float* __restrict__ b0, const float* __restrict__ b1,
    const float* __restrict__ b2)
{
  gemm_body<0>(blockIdx.z, blockIdx.y, blockIdx.x, A, B, Cv, vT, 1.0f,
               b0, b1, b2, nullptr);
}

// score: round-4 XCD supertile swizzle (xcd presumed blockIdx%8).
__global__ __launch_bounds__(256) void k_score(
    const short* __restrict__ A, const short* __restrict__ B,
    void* __restrict__ Cv, float scale, float* __restrict__ rowsum)
{
  const int b = blockIdx.x;
  const int xcd = b & 7, r = b >> 3;
  const int z = r >> 5;
  const int pair = (r >> 4) & 1, mem = r & 15;
  const int s = pair * 8 + xcd;
  const int tm = (s >> 2) * 4 + (mem >> 2);
  const int tn = (s & 3) * 4 + (mem & 3);
  gemm_body<1>(z, tm, tn, A, B, Cv, nullptr, scale,
               nullptr, nullptr, nullptr, rowsum);
}

// pv: round-4 XCD supertile swizzle.
__global__ __launch_bounds__(256) void k_pv(
    const short* __restrict__ A, const short* __restrict__ B,
    void* __restrict__ Cv, float* __restrict__ rowsum)
{
  const int b = blockIdx.x;
  const int s = b & 7, r = b >> 3;
  const int z = r >> 4;
  const int mem = r & 15;
  const int tm = (s >> 1) * 4 + (mem >> 2);
  const int tn = (s & 1) * 4 + (mem & 3);
  gemm_body<2>(z, tm, tn, A, B, Cv, nullptr, 1.0f,
               nullptr, nullptr, nullptr, rowsum);
}

// prep: blocks [0,8192) cvt x -> bf16; [8192,11264) W^T -> bf16; 11264 zero rs
__global__ __launch_bounds__(256) void k_prep(
    const float4* __restrict__ x, ushort4* __restrict__ xb,
    const float* __restrict__ Wq, const float* __restrict__ Wk,
    const float* __restrict__ Wv, short* __restrict__ WT,
    float* __restrict__ rs)
{
  __shared__ short tile[32][33];
  const int b = blockIdx.x;
  if (b < 8192) {
    const long i = (long)b * 256 + threadIdx.x;
    float4 v = x[i];
    ushort4 o;
    o.x = f2bf(v.x); o.y = f2bf(v.y); o.z = f2bf(v.z); o.w = f2bf(v.w);
    xb[i] = o;
  } else if (b < 11264) {
    const int idx = b - 8192;
    const int z = idx >> 10, rem = idx & 1023;
    const float* W = (z == 0) ? Wq : ((z == 1) ? Wk : Wv);
    short* d = WT + (long)z * 1024 * 1024;
    const int n0 = (rem & 31) * 32, d0 = (rem >> 5) * 32;
    const int tx = threadIdx.x & 31, ty = threadIdx.x >> 5;
#pragma unroll
    for (int p = 0; p < 4; ++p)
      tile[ty + p * 8][tx] = (short)f2bf(W[(long)(d0 + ty + p * 8) * 1024 + n0 + tx]);
    __syncthreads();
#pragma unroll
    for (int p = 0; p < 4; ++p)
      d[(long)(n0 + ty + p * 8) * 1024 + d0 + tx] = tile[tx][ty + p * 8];
  } else {
#pragma unroll
    for (int p = 0; p < 32; ++p)
      rs[p * 256 + threadIdx.x] = 0.0f;
  }
}

extern "C" void kernel_launch(void* const* d_in, const int* in_sizes, int n_in,
                              void* d_out, int out_size, void* d_ws, size_t ws_size,
                              hipStream_t stream) {
  const float* x  = (const float*)d_in[0];
  const float* Wq = (const float*)d_in[1];
  const float* bq = (const float*)d_in[2];
  const float* Wk = (const float*)d_in[3];
  const float* bk = (const float*)d_in[4];
  const float* Wv = (const float*)d_in[5];
  const float* bv = (const float*)d_in[6];

  char* ws = (char*)d_ws;
  short* xb  = (short*)(ws);                  // 16 MB
  short* wt  = (short*)(ws + 16777216);       // 6 MB
  short* qkv = (short*)(ws + 23068672);       // 48 MB: q | k | vT
  short* Pp  = (short*)(ws + 73400320);       // 32 MB: [4][2048][2048] bf16
  float* rs  = (float*)(ws + 106954752);      // 32 KB: [4][2048] fp32
  short* vT  = qkv + 2L * 8388608;            // [4][1024][2048] bf16

  // 1. prep: xb, wt, rowsum=0
  k_prep<<<11265, 256, 0, stream>>>((const float4*)x, (ushort4*)xb,
                                    Wq, Wk, Wv, wt, rs);
  // 2. q,k = x@W+b (bf16); v written transposed into vT
  k_qkv<<<dim3(8, 64, 3), 256, 0, stream>>>(xb, wt, qkv, vT, bq, bk, bv);
  // 3. P' = exp2(q@k^T * scale*log2e), bf16 + rowsum atomics
  k_score<<<1024, 256, 0, stream>>>(qkv, qkv + 8388608, Pp,
                                    0.03125f * 1.44269504088896f, rs);
  // 4. out = (P' @ vT^T) / rowsum  (fp32 -> d_out)
  k_pv<<<512, 256, 0, stream>>>(Pp, vT, d_out, rs);
}